// Round 3
// baseline (53.406 us; speedup 1.0000x reference)
//
#include <hip/hip_runtime.h>
#include <math.h>

// Cox partial log-likelihood, N=8192 — fused single-kernel version.
// loss = -mean_i ( (hazard[i] - log( sum_j exp(hazard[j]) * [time[j]>=time[i]] )) * censor[i] )
//
// R3: R2 showed the 2-kernel structure's dispatch overhead + serialized
// single-block finalize dominate (kernels sum ~6us of 16us). Fuse into ONE
// kernel node via the "last block finalizes" pattern:
//   - 2048 blocks = 256 i-chunks x 8 j-splits; 8KB LDS/block -> 8 blocks/CU
//     -> 32 waves/CU (8/SIMD).
//   - each block writes 32 partial risk sums; the last block per i-chunk
//     (device-scope counter) computes that chunk's (h - log(rs))*c and a
//     group loss; the last group-finalizer sums 256 group losses -> out.
//   - counters are poison-tolerant (atomicCAS(0xAAAAAAAA -> 0) before the
//     first add; winners reset to 0 for the next graph replay). No memset
//     node, no spin-waits, deterministic fixed-order summation.

#define COX_N    8192
#define COX_TPB  256
#define JSPLIT   8
#define JCHUNK   (COX_N / JSPLIT)            // 1024
#define IPT      8                           // i-values per wave
#define WPB      (COX_TPB / 64)              // 4 waves/block
#define I_PER_BLOCK (WPB * IPT)              // 32
#define ICHUNKS  (COX_N / I_PER_BLOCK)       // 256
#define POISON   0xAAAAAAAAu
#define CNT_STRIDE_U32 16                    // 64B per counter -> no line sharing

// ws layout:
//   floats [0, JSPLIT*COX_N)                      : partial risk sums
//   floats [GL_OFF, GL_OFF+ICHUNKS)               : per-i-chunk loss partials
//   u32    [CNT_OFF_U32 + ic*CNT_STRIDE_U32]      : per-i-chunk counters
//   u32    [CNT2_OFF_U32]                         : group-finalizer counter
#define GL_OFF        (JSPLIT * COX_N)                       // 65536 floats
#define CNT_OFF_U32   (GL_OFF + ICHUNKS)                     // 65792 (16B-aligned)
#define CNT2_OFF_U32  (CNT_OFF_U32 + ICHUNKS * CNT_STRIDE_U32)

__global__ __launch_bounds__(COX_TPB, 8) void cox_fused(const float* __restrict__ hazard,
                                                        const float* __restrict__ time_,
                                                        const float* __restrict__ censor,
                                                        float* __restrict__ ws_f,
                                                        unsigned int* __restrict__ ws_u,
                                                        float* __restrict__ out) {
    __shared__ __align__(16) float t_lds[JCHUNK];
    __shared__ __align__(16) float e_lds[JCHUNK];
    __shared__ int s_win;

    const int t  = threadIdx.x;
    const int ic = blockIdx.x & (ICHUNKS - 1);   // i-chunk 0..255
    const int js = blockIdx.x >> 8;              // j-split 0..7
    const int jbase = js * JCHUNK;

    const int lane = t & 63;
    const int wid  = t >> 6;
    const int iBase = ic * I_PER_BLOCK + wid * IPT;

    // i-side times (L2-hot broadcast reads).
    float ti[IPT];
    #pragma unroll
    for (int ii = 0; ii < IPT; ++ii) ti[ii] = time_[iBase + ii];

    // Stage this block's 1024-j chunk: exactly one float4 per thread.
    {
        const float4 tv = reinterpret_cast<const float4*>(time_ + jbase)[t];
        const float4 hv = reinterpret_cast<const float4*>(hazard + jbase)[t];
        float4 ev;
        ev.x = expf(hv.x); ev.y = expf(hv.y);
        ev.z = expf(hv.z); ev.w = expf(hv.w);
        reinterpret_cast<float4*>(t_lds)[t] = tv;
        reinterpret_cast<float4*>(e_lds)[t] = ev;
    }
    __syncthreads();

    float acc[IPT];
    #pragma unroll
    for (int ii = 0; ii < IPT; ++ii) acc[ii] = 0.0f;

    // Sweep the 1024-j chunk: lane l reads j = k*256 + 4l (+0..3), contiguous
    // 1KB/wave ds_read_b128 -> conflict-free. 4 k-iterations, fully unrolled.
    #pragma unroll
    for (int k = 0; k < JCHUNK / 256; ++k) {
        const int j = (k << 8) + (lane << 2);
        const float4 tj = *reinterpret_cast<const float4*>(t_lds + j);
        const float4 ej = *reinterpret_cast<const float4*>(e_lds + j);
        const float tjv[4] = {tj.x, tj.y, tj.z, tj.w};
        const float ejv[4] = {ej.x, ej.y, ej.z, ej.w};
        #pragma unroll
        for (int c = 0; c < 4; ++c) {
            #pragma unroll
            for (int ii = 0; ii < IPT; ++ii) {
                acc[ii] += (tjv[c] >= ti[ii]) ? ejv[c] : 0.0f;
            }
        }
    }

    // Butterfly-reduce each accumulator across the 64-lane wave.
    #pragma unroll
    for (int ii = 0; ii < IPT; ++ii) {
        float r = acc[ii];
        #pragma unroll
        for (int off = 32; off > 0; off >>= 1) r += __shfl_xor(r, off, 64);
        acc[ii] = r;
    }

    if (lane == 0) {
        #pragma unroll
        for (int ii = 0; ii < IPT; ++ii)
            ws_f[js * COX_N + iBase + ii] = acc[ii];
    }

    // ---- level 1: last j-split block for this i-chunk finalizes the chunk ----
    __syncthreads();                              // all partial stores issued
    if (t == 0) {
        __threadfence();                          // release partials device-wide
        unsigned int* cnt = ws_u + CNT_OFF_U32 + ic * CNT_STRIDE_U32;
        atomicCAS(cnt, POISON, 0u);               // first-touch poison clear
        const unsigned int old = atomicAdd(cnt, 1u);
        const int w = (old == JSPLIT - 1);
        if (w) *cnt = 0u;                         // reset for next replay
        s_win = w;
    }
    __syncthreads();

    if (s_win && t < 32) {                        // wave 0, lanes 0..31
        __threadfence();                          // acquire other blocks' partials
        const int i = ic * I_PER_BLOCK + t;
        float rs = 0.0f;
        #pragma unroll
        for (int p = 0; p < JSPLIT; ++p) rs += ws_f[p * COX_N + i];
        float li = (hazard[i] - logf(rs)) * censor[i];
        #pragma unroll
        for (int off = 16; off > 0; off >>= 1) li += __shfl_xor(li, off, 64);

        // ---- level 2: last group-finalizer sums the 256 group losses ----
        int win2 = 0;
        if (t == 0) {
            ws_f[GL_OFF + ic] = li;
            __threadfence();
            unsigned int* cnt2 = ws_u + CNT2_OFF_U32;
            atomicCAS(cnt2, POISON, 0u);
            const unsigned int old2 = atomicAdd(cnt2, 1u);
            win2 = (old2 == ICHUNKS - 1);
            if (win2) *cnt2 = 0u;
        }
        win2 = __shfl(win2, 0, 64);
        if (win2) {
            __threadfence();
            float tot = 0.0f;
            #pragma unroll
            for (int p = 0; p < ICHUNKS / 32; ++p) tot += ws_f[GL_OFF + t + 32 * p];
            #pragma unroll
            for (int off = 16; off > 0; off >>= 1) tot += __shfl_xor(tot, off, 64);
            if (t == 0) out[0] = -tot / (float)COX_N;
        }
    }
}

extern "C" void kernel_launch(void* const* d_in, const int* in_sizes, int n_in,
                              void* d_out, int out_size, void* d_ws, size_t ws_size,
                              hipStream_t stream) {
    const float* hazard = (const float*)d_in[0];
    const float* time_  = (const float*)d_in[1];
    const float* censor = (const float*)d_in[2];
    float* out = (float*)d_out;
    float* ws_f = (float*)d_ws;
    unsigned int* ws_u = (unsigned int*)d_ws;

    hipLaunchKernelGGL(cox_fused, dim3(ICHUNKS * JSPLIT), dim3(COX_TPB), 0, stream,
                       hazard, time_, censor, ws_f, ws_u, out);
}

// Round 4
// 13.529 us; speedup vs baseline: 3.9476x; 3.9476x over previous
//
#include <hip/hip_runtime.h>
#include <math.h>

// Cox partial log-likelihood, N=8192.
// loss = -mean_i ( (hazard[i] - log( sum_j exp(hazard[j]) * [time[j]>=time[i]] )) * censor[i] )
//
// R4: back to 2 clean dispatches (R3's fused device-scope-fence version was
// fence-bound: 53us, VALUBusy 10%).
//  K1: JSPLIT=8 -> 8KB LDS/block, 2048 blocks = 8 blocks/CU = 8 waves/SIMD.
//      Conflict-free float4 LDS sweep, IPT=8, merged-butterfly reduction
//      (17 shuffles instead of 48). Block 0 also zeroes out[0] (runs before K2).
//  K2: 32 blocks x 256 threads; thread i sums 8 partials, (h-log(rs))*c,
//      block-reduce, one fp32 atomicAdd per block into out (32 total; order
//      error ~1e-6 << 8.4e-2 threshold).

#define COX_N    8192
#define COX_TPB  256
#define JSPLIT   8
#define JCHUNK   (COX_N / JSPLIT)            // 1024
#define IPT      8                           // i-values per wave
#define WPB      (COX_TPB / 64)              // 4 waves/block
#define I_PER_BLOCK (WPB * IPT)              // 32
#define ICHUNKS  (COX_N / I_PER_BLOCK)       // 256
// grid K1 = ICHUNKS * JSPLIT = 2048 blocks -> 8 blocks/CU

__device__ __forceinline__ float merge_pair(float a, float b, int takeB, int off) {
    // Pair-reduce a and b over lanes differing in `off`, keep b-side if takeB.
    float am = a + __shfl_xor(a, off, 64);
    float bm = b + __shfl_xor(b, off, 64);
    return takeB ? bm : am;
}

__global__ __launch_bounds__(COX_TPB, 8) void cox_main(const float* __restrict__ hazard,
                                                       const float* __restrict__ time_,
                                                       float* __restrict__ partials,
                                                       float* __restrict__ out) {
    __shared__ __align__(16) float t_lds[JCHUNK];
    __shared__ __align__(16) float e_lds[JCHUNK];

    const int t  = threadIdx.x;
    const int ic = blockIdx.x & (ICHUNKS - 1);   // i-chunk 0..255
    const int js = blockIdx.x >> 8;              // j-split 0..7
    const int jbase = js * JCHUNK;

    if (blockIdx.x == 0 && t == 0) out[0] = 0.0f;   // fresh accumulator each call

    const int lane = t & 63;
    const int wid  = t >> 6;
    const int iBase = ic * I_PER_BLOCK + wid * IPT;

    // i-side times (wave-uniform -> scalar loads, L2-hot).
    float ti[IPT];
    #pragma unroll
    for (int ii = 0; ii < IPT; ++ii) ti[ii] = time_[iBase + ii];

    // Stage this block's 1024-j chunk: exactly one float4 per thread.
    {
        const float4 tv = reinterpret_cast<const float4*>(time_ + jbase)[t];
        const float4 hv = reinterpret_cast<const float4*>(hazard + jbase)[t];
        float4 ev;
        ev.x = expf(hv.x); ev.y = expf(hv.y);
        ev.z = expf(hv.z); ev.w = expf(hv.w);
        reinterpret_cast<float4*>(t_lds)[t] = tv;
        reinterpret_cast<float4*>(e_lds)[t] = ev;
    }
    __syncthreads();

    float acc[IPT];
    #pragma unroll
    for (int ii = 0; ii < IPT; ++ii) acc[ii] = 0.0f;

    // Sweep the 1024-j chunk: lane l reads j = k*256 + 4l (+0..3), contiguous
    // 1KB/wave ds_read_b128 -> conflict-free. 4 k-iterations, fully unrolled.
    #pragma unroll
    for (int k = 0; k < JCHUNK / 256; ++k) {
        const int j = (k << 8) + (lane << 2);
        const float4 tj = *reinterpret_cast<const float4*>(t_lds + j);
        const float4 ej = *reinterpret_cast<const float4*>(e_lds + j);
        const float tjv[4] = {tj.x, tj.y, tj.z, tj.w};
        const float ejv[4] = {ej.x, ej.y, ej.z, ej.w};
        #pragma unroll
        for (int c = 0; c < 4; ++c) {
            #pragma unroll
            for (int ii = 0; ii < IPT; ++ii) {
                acc[ii] += (tjv[c] >= ti[ii]) ? ejv[c] : 0.0f;
            }
        }
    }

    // Merged butterfly: reduce all 8 accs with 17 shuffles. After this,
    // lane l holds the full 64-lane sum of acc[l & 7].
    const int b0 = lane & 1, b1 = lane & 2, b2 = lane & 4;
    float w0 = merge_pair(acc[0], acc[1], b0, 1);
    float w1 = merge_pair(acc[2], acc[3], b0, 1);
    float w2 = merge_pair(acc[4], acc[5], b0, 1);
    float w3 = merge_pair(acc[6], acc[7], b0, 1);
    float x0 = merge_pair(w0, w1, b1, 2);
    float x1 = merge_pair(w2, w3, b1, 2);
    float y  = merge_pair(x0, x1, b2, 4);
    y += __shfl_xor(y, 8, 64);
    y += __shfl_xor(y, 16, 64);
    y += __shfl_xor(y, 32, 64);

    if (lane < IPT)
        partials[js * COX_N + iBase + lane] = y;
}

__global__ __launch_bounds__(COX_TPB) void cox_finalize(const float* __restrict__ partials,
                                                        const float* __restrict__ hazard,
                                                        const float* __restrict__ censor,
                                                        float* __restrict__ out) {
    __shared__ float red[WPB];
    const int t = threadIdx.x;
    const int i = blockIdx.x * COX_TPB + t;

    float rs = 0.0f;
    #pragma unroll
    for (int p = 0; p < JSPLIT; ++p) rs += partials[p * COX_N + i];
    float li = (hazard[i] - logf(rs)) * censor[i];

    #pragma unroll
    for (int off = 32; off > 0; off >>= 1) li += __shfl_xor(li, off, 64);
    if ((t & 63) == 0) red[t >> 6] = li;
    __syncthreads();
    if (t == 0) {
        float bs = red[0] + red[1] + red[2] + red[3];
        atomicAdd(out, -bs / (float)COX_N);
    }
}

extern "C" void kernel_launch(void* const* d_in, const int* in_sizes, int n_in,
                              void* d_out, int out_size, void* d_ws, size_t ws_size,
                              hipStream_t stream) {
    const float* hazard = (const float*)d_in[0];
    const float* time_  = (const float*)d_in[1];
    const float* censor = (const float*)d_in[2];
    float* out = (float*)d_out;
    float* partials = (float*)d_ws;               // 8 * 8192 floats = 256KB

    hipLaunchKernelGGL(cox_main, dim3(ICHUNKS * JSPLIT), dim3(COX_TPB), 0, stream,
                       hazard, time_, partials, out);
    hipLaunchKernelGGL(cox_finalize, dim3(COX_N / COX_TPB), dim3(COX_TPB), 0, stream,
                       partials, hazard, censor, out);
}